// Round 2
// baseline (1959.693 us; speedup 1.0000x reference)
//
#include <hip/hip_runtime.h>

#define C_ 256
#define HW_ 65536
#define IMG_ (C_*HW_)

typedef __attribute__((ext_vector_type(4))) float f32x4;
typedef __attribute__((ext_vector_type(8))) short s16x8;
typedef unsigned long long ull;

__device__ __forceinline__ ushort f2bf(float f) {
  union { float f; unsigned u; } v; v.f = f;
  unsigned u = v.u;
  return (ushort)((u + 0x7fffu + ((u >> 16) & 1u)) >> 16);
}

__device__ __forceinline__ s16x8 ldfrag(const ushort* p) {
  s16x8 v;
  ((ull*)&v)[0] = *(const ull*)(p);
  ((ull*)&v)[1] = *(const ull*)(p + 4);
  return v;
}

__device__ __forceinline__ void st8(ushort* d, uint4 u) {
  *(ull*)(d)     = ((ull*)&u)[0];
  *(ull*)(d + 4) = ((ull*)&u)[1];
}

// ---------------- per-plane stats ----------------
__global__ void k_stats1(const float* __restrict__ x, float2* __restrict__ part) {
  int bid = blockIdx.x;                  // 1024 = (b,c) planes
  int tid = threadIdx.x;
  const f32x4* p = (const f32x4*)(x + (size_t)bid*65536);
  float s = 0.f, ss = 0.f;
  #pragma unroll 4
  for (int i = tid; i < 16384; i += 256) {
    f32x4 v = p[i];
    s  += v[0]+v[1]+v[2]+v[3];
    ss += v[0]*v[0]+v[1]*v[1]+v[2]*v[2]+v[3]*v[3];
  }
  __shared__ float sa[256], sb[256];
  sa[tid]=s; sb[tid]=ss; __syncthreads();
  for (int k=128;k>0;k>>=1){
    if (tid<k){ sa[tid]+=sa[tid+k]; sb[tid]+=sb[tid+k]; }
    __syncthreads();
  }
  if (tid==0) part[bid] = make_float2(sa[0], sb[0]);
}

// ---------------- fold GN stats into per-batch bf16 weights ----------------
__global__ void k_fold(const float* __restrict__ wq, const float* __restrict__ bq,
                       const float* __restrict__ wk, const float* __restrict__ bk,
                       const float* __restrict__ wv, const float* __restrict__ bv,
                       const float* __restrict__ wo, const float* __restrict__ bo,
                       const float* __restrict__ gamma, const float* __restrict__ beta,
                       const float2* __restrict__ part,
                       ushort* __restrict__ wAll, ushort* __restrict__ woE,
                       float* __restrict__ biasAll) {
  int id = blockIdx.x, co = threadIdx.x;
  if (id == 12) {
    for (int c4 = 0; c4 < 64; ++c4) {
      ushort4 pk;
      pk.x = f2bf(wo[co*256 + c4*4 + 0]);
      pk.y = f2bf(wo[co*256 + c4*4 + 1]);
      pk.z = f2bf(wo[co*256 + c4*4 + 2]);
      pk.w = f2bf(wo[co*256 + c4*4 + 3]);
      *(ushort4*)&woE[co*256 + c4*4] = pk;
    }
    biasAll[3072 + co] = bo[co];
    return;
  }
  int m = id >> 2, b = id & 3;
  __shared__ float mean_s[32], rstd_s[32];
  __shared__ float aS[256], cS[256];
  if (co < 32) {
    float s = 0.f, ss = 0.f;
    for (int j = 0; j < 8; ++j) { float2 v = part[b*256 + co*8 + j]; s += v.x; ss += v.y; }
    float mean = s * (1.f/524288.f);
    float var  = ss * (1.f/524288.f) - mean*mean;
    mean_s[co] = mean; rstd_s[co] = rsqrtf(var + 1e-6f);
  }
  __syncthreads();
  { int g2 = co >> 3; float a = rstd_s[g2]*gamma[co]; aS[co] = a; cS[co] = beta[co] - mean_s[g2]*a; }
  __syncthreads();
  const float* W  = m==0 ? wq : m==1 ? wk : wv;
  const float* bi = m==0 ? bq : m==1 ? bk : bv;
  float s = (m==0) ? 0.0625f : 1.0f;
  float acc = bi[co];
  ushort* dst = wAll + ((size_t)(m*4 + b)*256 + co)*256;
  for (int c4 = 0; c4 < 64; ++c4) {
    ushort4 pk; float wv_;
    wv_ = W[co*256 + c4*4 + 0]; acc += wv_*cS[c4*4+0]; pk.x = f2bf(wv_*aS[c4*4+0]*s);
    wv_ = W[co*256 + c4*4 + 1]; acc += wv_*cS[c4*4+1]; pk.y = f2bf(wv_*aS[c4*4+1]*s);
    wv_ = W[co*256 + c4*4 + 2]; acc += wv_*cS[c4*4+2]; pk.z = f2bf(wv_*aS[c4*4+2]*s);
    wv_ = W[co*256 + c4*4 + 3]; acc += wv_*cS[c4*4+3]; pk.w = f2bf(wv_*aS[c4*4+3]*s);
    *(ushort4*)&dst[c4*4] = pk;
  }
  biasAll[m*1024 + b*256 + co] = acc * s;
}

// ---------------- fused QKV projection (GN pre-folded) ----------------
// mat 0/1: D[t][co] 128x256 -> Qt/Kt[win][t][c];  mat 2: D[co][t] 256x128 -> V[win][c][t]
__global__ __launch_bounds__(256) void k_qkv(const float* __restrict__ x,
    const ushort* __restrict__ wAll, const float* __restrict__ biasAll,
    ushort* __restrict__ Qt, ushort* __restrict__ Kt, ushort* __restrict__ V) {
  int g = blockIdx.x;
  int xcd = g & 7, i = g >> 3;
  int win = xcd*128 + i/6;
  int r6 = i % 6, mat = r6 >> 1, th = r6 & 1;
  int b = win >> 8, wy = (win >> 4) & 15, wx = win & 15;
  int tid = threadIdx.x, l = tid & 63, wid = tid >> 6, h = l >> 4;
  int t0 = th * 128;

  __shared__ __align__(16) ushort smem[17408];
  ushort* xt = smem;          // [128][36]
  ushort* wl = smem + 4608;   // [256][36]

  const ushort* wsrc = wAll + (size_t)(mat*4 + b)*65536;
  const float* xw = x + (size_t)b*IMG_ + wy*16*256 + wx*16;

  f32x4 acc[4][8];
  #pragma unroll
  for (int a = 0; a < 4; ++a)
    #pragma unroll
    for (int n = 0; n < 8; ++n) acc[a][n] = (f32x4){0.f,0.f,0.f,0.f};

  int arb = (mat < 2) ? (wid & 1)*64 : wid*64;
  int brb = (mat < 2) ? (wid >> 1)*128 : 0;
  const ushort* Asrc = (mat < 2) ? xt : wl;
  const ushort* Bsrc = (mat < 2) ? wl : xt;

  for (int ck = 0; ck < 8; ++ck) {
    int cb = ck*32;
    __syncthreads();
    // x -> xt transposed bf16 [t][ci]
    #pragma unroll
    for (int r = 0; r < 4; ++r) {
      int ci = r*8 + (l >> 3);
      int tl = wid*32 + 4*(l & 7);
      int tt = t0 + tl;
      const float* gp = xw + (size_t)(cb + ci)*HW_ + (tt >> 4)*256 + (tt & 15);
      f32x4 v = *(const f32x4*)gp;
      #pragma unroll
      for (int k = 0; k < 4; ++k) xt[(tl + k)*36 + ci] = f2bf(v[k]);
    }
    // weights -> wl [co][ci]
    {
      const ushort* wr = wsrc + tid*256 + cb;
      uint4 u0 = *(const uint4*)(wr);
      uint4 u1 = *(const uint4*)(wr + 8);
      uint4 u2 = *(const uint4*)(wr + 16);
      uint4 u3 = *(const uint4*)(wr + 24);
      ushort* d = wl + tid*36;
      st8(d, u0); st8(d + 8, u1); st8(d + 16, u2); st8(d + 24, u3);
    }
    __syncthreads();
    s16x8 af[4], bf[8];
    #pragma unroll
    for (int ms = 0; ms < 4; ++ms)
      af[ms] = ldfrag(&Asrc[(size_t)(arb + ms*16 + (l & 15))*36 + h*8]);
    #pragma unroll
    for (int ns = 0; ns < 8; ++ns)
      bf[ns] = ldfrag(&Bsrc[(size_t)(brb + ns*16 + (l & 15))*36 + h*8]);
    #pragma unroll
    for (int ms = 0; ms < 4; ++ms)
      #pragma unroll
      for (int ns = 0; ns < 8; ++ns)
        acc[ms][ns] = __builtin_amdgcn_mfma_f32_16x16x32_bf16(af[ms], bf[ns], acc[ms][ns], 0,0,0);
  }

  // epilogue via LDS slab -> wide stores
  int R = (mat < 2) ? 128 : 256;
  int C = (mat < 2) ? 256 : 128;
  ushort* dst = (mat == 0) ? Qt + (size_t)win*65536
              : (mat == 1) ? Kt + (size_t)win*65536
                           : V  + (size_t)win*65536;
  int row0 = (mat < 2) ? t0 : 0;
  int col0 = (mat < 2) ? 0 : t0;

  float bc[8]; f32x4 br[4];
  if (mat < 2) {
    #pragma unroll
    for (int ns = 0; ns < 8; ++ns)
      bc[ns] = biasAll[mat*1024 + b*256 + brb + ns*16 + (l & 15)];
  } else {
    #pragma unroll
    for (int ms = 0; ms < 4; ++ms)
      br[ms] = *(const f32x4*)&biasAll[2048 + b*256 + wid*64 + ms*16 + 4*h];
  }

  int nslab = C >> 6;
  for (int sl = 0; sl < nslab; ++sl) {
    __syncthreads();
    bool act = (mat < 2) ? ((wid >> 1) == (sl >> 1)) : true;
    if (act) {
      int nsb = (mat < 2) ? (sl & 1)*4 : sl*4;
      #pragma unroll
      for (int ms = 0; ms < 4; ++ms)
        #pragma unroll
        for (int k = 0; k < 4; ++k) {
          int ns = nsb + k;
          #pragma unroll
          for (int j = 0; j < 4; ++j) {
            int row = ((mat < 2) ? (wid & 1)*64 : wid*64) + ms*16 + 4*h + j;
            int lc = k*16 + (l & 15);
            float v = acc[ms][ns][j] + ((mat < 2) ? bc[ns] : br[ms][j]);
            smem[row*68 + lc] = f2bf(v);
          }
        }
    }
    __syncthreads();
    int np = R >> 5;
    for (int p = 0; p < np; ++p) {
      int rr = p*32 + (tid >> 3), seg = tid & 7;
      const ushort* sp = &smem[rr*68 + seg*8];
      uint4 v;
      ((ull*)&v)[0] = *(const ull*)sp;
      ((ull*)&v)[1] = *(const ull*)(sp + 4);
      *(uint4*)(dst + (size_t)(row0 + rr)*256 + col0 + sl*64 + seg*8) = v;
    }
  }
}

// ---------------- windowed attention ----------------
__global__ __launch_bounds__(256) void k_attn(const ushort* __restrict__ Qt,
    const ushort* __restrict__ Kt, const ushort* __restrict__ V,
    ushort* __restrict__ AO) {
  int g = blockIdx.x;
  int xcd = g & 7, i = g >> 3;
  int w = xcd*128 + (i >> 2), qt = i & 3;
  int q0 = qt * 64;
  int tid = threadIdx.x, l = tid & 63, wid = tid >> 6, h = l >> 4;
  __shared__ __align__(16) ushort Aq[64*36];
  __shared__ __align__(16) ushort BKV[256*36];
  __shared__ __align__(16) ushort P[64*276];
  __shared__ float red[2][4][64];
  const ushort* qbase = Qt + (size_t)w*65536;
  const ushort* kbase = Kt + (size_t)w*65536;
  const ushort* vbase = V  + (size_t)w*65536;
  int nbase = wid * 64;

  f32x4 accS[4][4];
  #pragma unroll
  for (int a=0;a<4;a++)
    #pragma unroll
    for (int n=0;n<4;n++) accS[a][n] = (f32x4){0.f,0.f,0.f,0.f};

  for (int ck = 0; ck < 8; ++ck) {
    int cb = ck*32;
    __syncthreads();
    { int r = tid >> 2, seg = tid & 3;
      uint4 u = *(const uint4*)(qbase + (size_t)(q0 + r)*256 + cb + seg*8);
      st8(&Aq[r*36 + seg*8], u); }
    { const ushort* kr = kbase + (size_t)tid*256 + cb;
      #pragma unroll
      for (int s4 = 0; s4 < 4; ++s4) {
        uint4 u = *(const uint4*)(kr + s4*8);
        st8(&BKV[tid*36 + s4*8], u);
      } }
    __syncthreads();
    s16x8 af[4];
    #pragma unroll
    for (int ms = 0; ms < 4; ++ms)
      af[ms] = ldfrag(&Aq[(ms*16 + (l & 15))*36 + h*8]);
    #pragma unroll
    for (int ns = 0; ns < 4; ++ns) {
      s16x8 bf = ldfrag(&BKV[(nbase + ns*16 + (l & 15))*36 + h*8]);
      #pragma unroll
      for (int ms = 0; ms < 4; ++ms)
        accS[ms][ns] = __builtin_amdgcn_mfma_f32_16x16x32_bf16(af[ms], bf, accS[ms][ns], 0,0,0);
    }
  }

  // softmax over k
  float mx[4][4];
  #pragma unroll
  for (int ms=0;ms<4;ms++)
    #pragma unroll
    for (int j=0;j<4;j++) {
      float m_ = fmaxf(fmaxf(accS[ms][0][j], accS[ms][1][j]),
                       fmaxf(accS[ms][2][j], accS[ms][3][j]));
      #pragma unroll
      for (int msk=1; msk<16; msk<<=1) m_ = fmaxf(m_, __shfl_xor(m_, msk));
      mx[ms][j] = m_;
    }
  if ((l & 15) == 0) {
    #pragma unroll
    for (int ms=0;ms<4;ms++)
      #pragma unroll
      for (int j=0;j<4;j++) red[0][wid][ms*16 + 4*h + j] = mx[ms][j];
  }
  __syncthreads();
  float sj[4][4];
  #pragma unroll
  for (int ms=0;ms<4;ms++)
    #pragma unroll
    for (int j=0;j<4;j++) {
      int row = ms*16 + 4*h + j;
      float gm = fmaxf(fmaxf(red[0][0][row], red[0][1][row]),
                       fmaxf(red[0][2][row], red[0][3][row]));
      float s_ = 0.f;
      #pragma unroll
      for (int ns=0;ns<4;ns++) {
        float p = __expf(accS[ms][ns][j] - gm);
        accS[ms][ns][j] = p;
        s_ += p;
      }
      #pragma unroll
      for (int msk=1; msk<16; msk<<=1) s_ += __shfl_xor(s_, msk);
      sj[ms][j] = s_;
    }
  if ((l & 15) == 0) {
    #pragma unroll
    for (int ms=0;ms<4;ms++)
      #pragma unroll
      for (int j=0;j<4;j++) red[1][wid][ms*16 + 4*h + j] = sj[ms][j];
  }
  __syncthreads();
  float rinv[4][4];
  #pragma unroll
  for (int ms=0;ms<4;ms++)
    #pragma unroll
    for (int j=0;j<4;j++) {
      int row = ms*16 + 4*h + j;
      rinv[ms][j] = 1.f / (red[1][0][row]+red[1][1][row]+red[1][2][row]+red[1][3][row]);
    }
  #pragma unroll
  for (int ms=0;ms<4;ms++)
    #pragma unroll
    for (int j=0;j<4;j++)
      #pragma unroll
      for (int ns=0;ns<4;ns++)
        P[(ms*16 + 4*h + j)*276 + nbase + ns*16 + (l & 15)] = f2bf(accS[ms][ns][j]);

  // PV
  f32x4 accO[4][4];
  #pragma unroll
  for (int a=0;a<4;a++)
    #pragma unroll
    for (int n=0;n<4;n++) accO[a][n] = (f32x4){0.f,0.f,0.f,0.f};

  for (int kt = 0; kt < 8; ++kt) {
    __syncthreads();
    { const ushort* vr = vbase + (size_t)tid*256 + kt*32;
      #pragma unroll
      for (int s4 = 0; s4 < 4; ++s4) {
        uint4 u = *(const uint4*)(vr + s4*8);
        st8(&BKV[tid*36 + s4*8], u);
      } }
    __syncthreads();
    s16x8 ap[4];
    #pragma unroll
    for (int ms = 0; ms < 4; ++ms)
      ap[ms] = ldfrag(&P[(ms*16 + (l & 15))*276 + kt*32 + h*8]);
    #pragma unroll
    for (int ns = 0; ns < 4; ++ns) {
      s16x8 bf = ldfrag(&BKV[(nbase + ns*16 + (l & 15))*36 + h*8]);
      #pragma unroll
      for (int ms = 0; ms < 4; ++ms)
        accO[ms][ns] = __builtin_amdgcn_mfma_f32_16x16x32_bf16(ap[ms], bf, accO[ms][ns], 0,0,0);
    }
  }

  // wide AO store via P reuse
  __syncthreads();
  #pragma unroll
  for (int ms=0;ms<4;ms++)
    #pragma unroll
    for (int j=0;j<4;j++) {
      float rv = rinv[ms][j];
      int q = ms*16 + 4*h + j;
      #pragma unroll
      for (int ns=0;ns<4;ns++)
        P[q*276 + nbase + ns*16 + (l & 15)] = f2bf(accO[ms][ns][j] * rv);
    }
  __syncthreads();
  ushort* aob = AO + (size_t)w*65536;
  #pragma unroll
  for (int it = 0; it < 8; ++it) {
    int task = tid + 256*it;
    int r = task >> 5, seg = task & 31;
    const ushort* sp = &P[r*276 + seg*8];
    uint4 v;
    ((ull*)&v)[0] = *(const ull*)sp;
    ((ull*)&v)[1] = *(const ull*)(sp + 4);
    *(uint4*)(aob + (size_t)(q0 + r)*256 + seg*8) = v;
  }
}

// ---------------- output projection + residual ----------------
__global__ __launch_bounds__(512) void k_oproj(const float* __restrict__ x,
    const ushort* __restrict__ AO, const ushort* __restrict__ woE,
    const float* __restrict__ biasAll, float* __restrict__ y) {
  int g = blockIdx.x;
  int w = (g & 7)*128 + (g >> 3);
  int b = w >> 8, wy = (w >> 4) & 15, wx = w & 15;
  int tid = threadIdx.x, l = tid & 63, wid = tid >> 6, h = l >> 4;
  __shared__ __align__(16) ushort alds[256*36];
  __shared__ __align__(16) ushort wlds[256*36];
  const ushort* abase = AO + (size_t)w*65536;

  f32x4 acc[8][4];
  #pragma unroll
  for (int a=0;a<8;a++)
    #pragma unroll
    for (int n=0;n<4;n++) acc[a][n] = (f32x4){0.f,0.f,0.f,0.f};
  int mbase = (wid >> 2)*128, nbase = (wid & 3)*64;

  for (int ck = 0; ck < 8; ++ck) {
    int cb = ck*32;
    __syncthreads();
    { int row = tid >> 1, sg = (tid & 1)*2;
      #pragma unroll
      for (int q2 = 0; q2 < 2; ++q2) {
        int seg = sg + q2;
        uint4 u  = *(const uint4*)(woE + (size_t)row*256 + cb + seg*8);
        st8(&wlds[row*36 + seg*8], u);
        uint4 u2 = *(const uint4*)(abase + (size_t)row*256 + cb + seg*8);
        st8(&alds[row*36 + seg*8], u2);
      } }
    __syncthreads();
    s16x8 bf[4];
    #pragma unroll
    for (int ns = 0; ns < 4; ++ns)
      bf[ns] = ldfrag(&alds[(nbase + ns*16 + (l & 15))*36 + h*8]);
    #pragma unroll
    for (int ms = 0; ms < 8; ++ms) {
      s16x8 af = ldfrag(&wlds[(mbase + ms*16 + (l & 15))*36 + h*8]);
      #pragma unroll
      for (int ns = 0; ns < 4; ++ns)
        acc[ms][ns] = __builtin_amdgcn_mfma_f32_16x16x32_bf16(af, bf[ns], acc[ms][ns], 0,0,0);
    }
  }
  const float* bs = biasAll + 3072;
  const float* xbase = x + (size_t)b*IMG_ + wy*16*256 + wx*16;
  float* ybase = y + (size_t)b*IMG_ + wy*16*256 + wx*16;
  #pragma unroll
  for (int ms = 0; ms < 8; ++ms) {
    f32x4 b4 = *(const f32x4*)&bs[mbase + ms*16 + 4*h];
    #pragma unroll
    for (int j = 0; j < 4; ++j) {
      int o = mbase + ms*16 + 4*h + j;
      #pragma unroll
      for (int ns = 0; ns < 4; ++ns) {
        int t = nbase + ns*16 + (l & 15);
        size_t off = (size_t)o*HW_ + (t >> 4)*256 + (t & 15);
        ybase[off] = xbase[off] + acc[ms][ns][j] + b4[j];
      }
    }
  }
}

extern "C" void kernel_launch(void* const* d_in, const int* in_sizes, int n_in,
                              void* d_out, int out_size, void* d_ws, size_t ws_size,
                              hipStream_t stream) {
  const float* x     = (const float*)d_in[0];
  const float* gamma = (const float*)d_in[1];
  const float* beta  = (const float*)d_in[2];
  const float* wq = (const float*)d_in[3];
  const float* bq = (const float*)d_in[4];
  const float* wk = (const float*)d_in[5];
  const float* bk = (const float*)d_in[6];
  const float* wv = (const float*)d_in[7];
  const float* bv = (const float*)d_in[8];
  const float* wo = (const float*)d_in[9];
  const float* bo = (const float*)d_in[10];
  float* y = (float*)d_out;
  char* ws = (char*)d_ws;

  float2* part   = (float2*)ws;                        // 8 KB
  float*  biasAll= (float*)(ws + 8192);                // 13.3 KB
  ushort* wAll   = (ushort*)(ws + 32768);              // 1.5 MB
  ushort* woE    = (ushort*)(ws + 32768 + 1572864);    // 128 KB
  ushort* Qt     = (ushort*)(ws + 2097152);            // 134 MB (also AO)
  ushort* Kt = (ushort*)d_out;
  ushort* V  = (ushort*)d_out + (size_t)67108864;

  k_stats1<<<1024, 256, 0, stream>>>(x, part);
  k_fold<<<13, 256, 0, stream>>>(wq,bq,wk,bk,wv,bv,wo,bo,gamma,beta,part,wAll,woE,biasAll);
  k_qkv<<<6144, 256, 0, stream>>>(x, wAll, biasAll, Qt, Kt, V);
  k_attn<<<4096, 256, 0, stream>>>(Qt, Kt, V, Qt /*AO alias: disjoint rows*/);
  k_oproj<<<1024, 512, 0, stream>>>(x, Qt /*AO*/, woE, biasAll, y);
}

// Round 3
// 869.695 us; speedup vs baseline: 2.2533x; 2.2533x over previous
//
#include <hip/hip_runtime.h>

#define C_ 256
#define HW_ 65536
#define IMG_ (C_*HW_)

typedef __attribute__((ext_vector_type(4))) float f32x4;
typedef __attribute__((ext_vector_type(8))) short s16x8;
typedef unsigned long long ull;

__device__ __forceinline__ ushort f2bf(float f) {
  union { float f; unsigned u; } v; v.f = f;
  unsigned u = v.u;
  return (ushort)((u + 0x7fffu + ((u >> 16) & 1u)) >> 16);
}

__device__ __forceinline__ s16x8 ldfrag(const ushort* p) {
  s16x8 v;
  ((ull*)&v)[0] = *(const ull*)(p);
  ((ull*)&v)[1] = *(const ull*)(p + 4);
  return v;
}

__device__ __forceinline__ void st8(ushort* d, uint4 u) {
  *(ull*)(d)     = ((ull*)&u)[0];
  *(ull*)(d + 4) = ((ull*)&u)[1];
}

// ---------------- per-plane stats ----------------
__global__ void k_stats1(const float* __restrict__ x, float2* __restrict__ part) {
  int bid = blockIdx.x;                  // 1024 = (b,c) planes
  int tid = threadIdx.x;
  const f32x4* p = (const f32x4*)(x + (size_t)bid*65536);
  float s = 0.f, ss = 0.f;
  #pragma unroll 4
  for (int i = tid; i < 16384; i += 256) {
    f32x4 v = p[i];
    s  += v[0]+v[1]+v[2]+v[3];
    ss += v[0]*v[0]+v[1]*v[1]+v[2]*v[2]+v[3]*v[3];
  }
  __shared__ float sa[256], sb[256];
  sa[tid]=s; sb[tid]=ss; __syncthreads();
  for (int k=128;k>0;k>>=1){
    if (tid<k){ sa[tid]+=sa[tid+k]; sb[tid]+=sb[tid+k]; }
    __syncthreads();
  }
  if (tid==0) part[bid] = make_float2(sa[0], sb[0]);
}

// ---------------- fold GN stats into per-batch bf16 weights ----------------
__global__ void k_fold(const float* __restrict__ wq, const float* __restrict__ bq,
                       const float* __restrict__ wk, const float* __restrict__ bk,
                       const float* __restrict__ wv, const float* __restrict__ bv,
                       const float* __restrict__ wo, const float* __restrict__ bo,
                       const float* __restrict__ gamma, const float* __restrict__ beta,
                       const float2* __restrict__ part,
                       ushort* __restrict__ wAll, ushort* __restrict__ woE,
                       float* __restrict__ biasAll) {
  int id = blockIdx.x, co = threadIdx.x;
  if (id == 12) {
    for (int c4 = 0; c4 < 64; ++c4) {
      ushort4 pk;
      pk.x = f2bf(wo[co*256 + c4*4 + 0]);
      pk.y = f2bf(wo[co*256 + c4*4 + 1]);
      pk.z = f2bf(wo[co*256 + c4*4 + 2]);
      pk.w = f2bf(wo[co*256 + c4*4 + 3]);
      *(ushort4*)&woE[co*256 + c4*4] = pk;
    }
    biasAll[3072 + co] = bo[co];
    return;
  }
  int m = id >> 2, b = id & 3;
  __shared__ float mean_s[32], rstd_s[32];
  __shared__ float aS[256], cS[256];
  if (co < 32) {
    float s = 0.f, ss = 0.f;
    for (int j = 0; j < 8; ++j) { float2 v = part[b*256 + co*8 + j]; s += v.x; ss += v.y; }
    float mean = s * (1.f/524288.f);
    float var  = ss * (1.f/524288.f) - mean*mean;
    mean_s[co] = mean; rstd_s[co] = rsqrtf(var + 1e-6f);
  }
  __syncthreads();
  { int g2 = co >> 3; float a = rstd_s[g2]*gamma[co]; aS[co] = a; cS[co] = beta[co] - mean_s[g2]*a; }
  __syncthreads();
  const float* W  = m==0 ? wq : m==1 ? wk : wv;
  const float* bi = m==0 ? bq : m==1 ? bk : bv;
  float s = (m==0) ? 0.0625f : 1.0f;
  float acc = bi[co];
  ushort* dst = wAll + ((size_t)(m*4 + b)*256 + co)*256;
  for (int c4 = 0; c4 < 64; ++c4) {
    ushort4 pk; float wv_;
    wv_ = W[co*256 + c4*4 + 0]; acc += wv_*cS[c4*4+0]; pk.x = f2bf(wv_*aS[c4*4+0]*s);
    wv_ = W[co*256 + c4*4 + 1]; acc += wv_*cS[c4*4+1]; pk.y = f2bf(wv_*aS[c4*4+1]*s);
    wv_ = W[co*256 + c4*4 + 2]; acc += wv_*cS[c4*4+2]; pk.z = f2bf(wv_*aS[c4*4+2]*s);
    wv_ = W[co*256 + c4*4 + 3]; acc += wv_*cS[c4*4+3]; pk.w = f2bf(wv_*aS[c4*4+3]*s);
    *(ushort4*)&dst[c4*4] = pk;
  }
  biasAll[m*1024 + b*256 + co] = acc * s;
}

// ---------------- fused QKV projection (GN pre-folded) ----------------
// mat 0/1: D[t][co] 128x256 -> Qt/Kt[win][t][c];  mat 2: D[co][t] 256x128 -> V[win][c][t]
__global__ __launch_bounds__(256, 2) void k_qkv(const float* __restrict__ x,
    const ushort* __restrict__ wAll, const float* __restrict__ biasAll,
    ushort* __restrict__ Qt, ushort* __restrict__ Kt, ushort* __restrict__ V) {
  int g = blockIdx.x;
  int xcd = g & 7, i = g >> 3;
  int win = xcd*128 + i/6;
  int r6 = i % 6, mat = r6 >> 1, th = r6 & 1;
  int b = win >> 8, wy = (win >> 4) & 15, wx = win & 15;
  int tid = threadIdx.x, l = tid & 63, wid = tid >> 6, h = l >> 4;
  int t0 = th * 128;

  __shared__ __align__(16) ushort smem[17408];
  ushort* xt = smem;          // [128][36]
  ushort* wl = smem + 4608;   // [256][36]

  const ushort* wsrc = wAll + (size_t)(mat*4 + b)*65536;
  const float* xw = x + (size_t)b*IMG_ + wy*16*256 + wx*16;

  f32x4 acc[4][8];
  #pragma unroll
  for (int a = 0; a < 4; ++a)
    #pragma unroll
    for (int n = 0; n < 8; ++n) acc[a][n] = (f32x4){0.f,0.f,0.f,0.f};

  int arb = (mat < 2) ? (wid & 1)*64 : wid*64;
  int brb = (mat < 2) ? (wid >> 1)*128 : 0;
  const ushort* Asrc = (mat < 2) ? xt : wl;
  const ushort* Bsrc = (mat < 2) ? wl : xt;

  for (int ck = 0; ck < 8; ++ck) {
    int cb = ck*32;
    __syncthreads();
    // x -> xt transposed bf16 [t][ci]
    #pragma unroll
    for (int r = 0; r < 4; ++r) {
      int ci = r*8 + (l >> 3);
      int tl = wid*32 + 4*(l & 7);
      int tt = t0 + tl;
      const float* gp = xw + (size_t)(cb + ci)*HW_ + (tt >> 4)*256 + (tt & 15);
      f32x4 v = *(const f32x4*)gp;
      #pragma unroll
      for (int k = 0; k < 4; ++k) xt[(tl + k)*36 + ci] = f2bf(v[k]);
    }
    // weights -> wl [co][ci]
    {
      const ushort* wr = wsrc + tid*256 + cb;
      uint4 u0 = *(const uint4*)(wr);
      uint4 u1 = *(const uint4*)(wr + 8);
      uint4 u2 = *(const uint4*)(wr + 16);
      uint4 u3 = *(const uint4*)(wr + 24);
      ushort* d = wl + tid*36;
      st8(d, u0); st8(d + 8, u1); st8(d + 16, u2); st8(d + 24, u3);
    }
    __syncthreads();
    s16x8 af[4], bf[8];
    #pragma unroll
    for (int ms = 0; ms < 4; ++ms)
      af[ms] = ldfrag(&Asrc[(size_t)(arb + ms*16 + (l & 15))*36 + h*8]);
    #pragma unroll
    for (int ns = 0; ns < 8; ++ns)
      bf[ns] = ldfrag(&Bsrc[(size_t)(brb + ns*16 + (l & 15))*36 + h*8]);
    #pragma unroll
    for (int ms = 0; ms < 4; ++ms)
      #pragma unroll
      for (int ns = 0; ns < 8; ++ns)
        acc[ms][ns] = __builtin_amdgcn_mfma_f32_16x16x32_bf16(af[ms], bf[ns], acc[ms][ns], 0,0,0);
  }

  // ---- epilogue via LDS slab -> wide stores; ALL acc indices compile-time ----
  if (mat < 2) {
    ushort* dst = ((mat == 0) ? Qt : Kt) + (size_t)win*65536;
    float bc[8];
    #pragma unroll
    for (int ns = 0; ns < 8; ++ns)
      bc[ns] = biasAll[mat*1024 + b*256 + brb + ns*16 + (l & 15)];
    #pragma unroll
    for (int sl = 0; sl < 4; ++sl) {
      __syncthreads();
      if ((wid >> 1) == (sl >> 1)) {
        const int nsb = (sl & 1)*4;
        #pragma unroll
        for (int ms = 0; ms < 4; ++ms)
          #pragma unroll
          for (int k = 0; k < 4; ++k)
            #pragma unroll
            for (int j = 0; j < 4; ++j) {
              int row = (wid & 1)*64 + ms*16 + 4*h + j;
              smem[row*68 + k*16 + (l & 15)] = f2bf(acc[ms][nsb + k][j] + bc[nsb + k]);
            }
      }
      __syncthreads();
      #pragma unroll
      for (int p = 0; p < 4; ++p) {
        int rr = p*32 + (tid >> 3), seg = tid & 7;
        const ushort* sp = &smem[rr*68 + seg*8];
        uint4 v;
        ((ull*)&v)[0] = *(const ull*)sp;
        ((ull*)&v)[1] = *(const ull*)(sp + 4);
        *(uint4*)(dst + (size_t)(t0 + rr)*256 + sl*64 + seg*8) = v;
      }
    }
  } else {
    ushort* dst = V + (size_t)win*65536;
    f32x4 br[4];
    #pragma unroll
    for (int ms = 0; ms < 4; ++ms)
      br[ms] = *(const f32x4*)&biasAll[2048 + b*256 + wid*64 + ms*16 + 4*h];
    #pragma unroll
    for (int sl = 0; sl < 2; ++sl) {
      __syncthreads();
      {
        const int nsb = sl*4;
        #pragma unroll
        for (int ms = 0; ms < 4; ++ms)
          #pragma unroll
          for (int k = 0; k < 4; ++k)
            #pragma unroll
            for (int j = 0; j < 4; ++j) {
              int row = wid*64 + ms*16 + 4*h + j;
              smem[row*68 + k*16 + (l & 15)] = f2bf(acc[ms][nsb + k][j] + br[ms][j]);
            }
      }
      __syncthreads();
      #pragma unroll
      for (int p = 0; p < 8; ++p) {
        int rr = p*32 + (tid >> 3), seg = tid & 7;
        const ushort* sp = &smem[rr*68 + seg*8];
        uint4 v;
        ((ull*)&v)[0] = *(const ull*)sp;
        ((ull*)&v)[1] = *(const ull*)(sp + 4);
        *(uint4*)(dst + (size_t)rr*256 + t0 + sl*64 + seg*8) = v;
      }
    }
  }
}

// ---------------- windowed attention ----------------
__global__ __launch_bounds__(256, 2) void k_attn(const ushort* __restrict__ Qt,
    const ushort* __restrict__ Kt, const ushort* __restrict__ V,
    ushort* __restrict__ AO) {
  int g = blockIdx.x;
  int xcd = g & 7, i = g >> 3;
  int w = xcd*128 + (i >> 2), qt = i & 3;
  int q0 = qt * 64;
  int tid = threadIdx.x, l = tid & 63, wid = tid >> 6, h = l >> 4;
  __shared__ __align__(16) ushort Aq[64*36];
  __shared__ __align__(16) ushort BKV[256*36];
  __shared__ __align__(16) ushort P[64*276];
  __shared__ float red[2][4][64];
  const ushort* qbase = Qt + (size_t)w*65536;
  const ushort* kbase = Kt + (size_t)w*65536;
  const ushort* vbase = V  + (size_t)w*65536;
  int nbase = wid * 64;

  f32x4 accS[4][4];
  #pragma unroll
  for (int a=0;a<4;a++)
    #pragma unroll
    for (int n=0;n<4;n++) accS[a][n] = (f32x4){0.f,0.f,0.f,0.f};

  for (int ck = 0; ck < 8; ++ck) {
    int cb = ck*32;
    __syncthreads();
    { int r = tid >> 2, seg = tid & 3;
      uint4 u = *(const uint4*)(qbase + (size_t)(q0 + r)*256 + cb + seg*8);
      st8(&Aq[r*36 + seg*8], u); }
    { const ushort* kr = kbase + (size_t)tid*256 + cb;
      #pragma unroll
      for (int s4 = 0; s4 < 4; ++s4) {
        uint4 u = *(const uint4*)(kr + s4*8);
        st8(&BKV[tid*36 + s4*8], u);
      } }
    __syncthreads();
    s16x8 af[4];
    #pragma unroll
    for (int ms = 0; ms < 4; ++ms)
      af[ms] = ldfrag(&Aq[(ms*16 + (l & 15))*36 + h*8]);
    #pragma unroll
    for (int ns = 0; ns < 4; ++ns) {
      s16x8 bf = ldfrag(&BKV[(nbase + ns*16 + (l & 15))*36 + h*8]);
      #pragma unroll
      for (int ms = 0; ms < 4; ++ms)
        accS[ms][ns] = __builtin_amdgcn_mfma_f32_16x16x32_bf16(af[ms], bf, accS[ms][ns], 0,0,0);
    }
  }

  // softmax over k
  float mx[4][4];
  #pragma unroll
  for (int ms=0;ms<4;ms++)
    #pragma unroll
    for (int j=0;j<4;j++) {
      float m_ = fmaxf(fmaxf(accS[ms][0][j], accS[ms][1][j]),
                       fmaxf(accS[ms][2][j], accS[ms][3][j]));
      #pragma unroll
      for (int msk=1; msk<16; msk<<=1) m_ = fmaxf(m_, __shfl_xor(m_, msk));
      mx[ms][j] = m_;
    }
  if ((l & 15) == 0) {
    #pragma unroll
    for (int ms=0;ms<4;ms++)
      #pragma unroll
      for (int j=0;j<4;j++) red[0][wid][ms*16 + 4*h + j] = mx[ms][j];
  }
  __syncthreads();
  float sj[4][4];
  #pragma unroll
  for (int ms=0;ms<4;ms++)
    #pragma unroll
    for (int j=0;j<4;j++) {
      int row = ms*16 + 4*h + j;
      float gm = fmaxf(fmaxf(red[0][0][row], red[0][1][row]),
                       fmaxf(red[0][2][row], red[0][3][row]));
      float s_ = 0.f;
      #pragma unroll
      for (int ns=0;ns<4;ns++) {
        float p = __expf(accS[ms][ns][j] - gm);
        accS[ms][ns][j] = p;
        s_ += p;
      }
      #pragma unroll
      for (int msk=1; msk<16; msk<<=1) s_ += __shfl_xor(s_, msk);
      sj[ms][j] = s_;
    }
  if ((l & 15) == 0) {
    #pragma unroll
    for (int ms=0;ms<4;ms++)
      #pragma unroll
      for (int j=0;j<4;j++) red[1][wid][ms*16 + 4*h + j] = sj[ms][j];
  }
  __syncthreads();
  float rinv[4][4];
  #pragma unroll
  for (int ms=0;ms<4;ms++)
    #pragma unroll
    for (int j=0;j<4;j++) {
      int row = ms*16 + 4*h + j;
      rinv[ms][j] = 1.f / (red[1][0][row]+red[1][1][row]+red[1][2][row]+red[1][3][row]);
    }
  #pragma unroll
  for (int ms=0;ms<4;ms++)
    #pragma unroll
    for (int j=0;j<4;j++)
      #pragma unroll
      for (int ns=0;ns<4;ns++)
        P[(ms*16 + 4*h + j)*276 + nbase + ns*16 + (l & 15)] = f2bf(accS[ms][ns][j]);

  // PV
  f32x4 accO[4][4];
  #pragma unroll
  for (int a=0;a<4;a++)
    #pragma unroll
    for (int n=0;n<4;n++) accO[a][n] = (f32x4){0.f,0.f,0.f,0.f};

  for (int kt = 0; kt < 8; ++kt) {
    __syncthreads();
    { const ushort* vr = vbase + (size_t)tid*256 + kt*32;
      #pragma unroll
      for (int s4 = 0; s4 < 4; ++s4) {
        uint4 u = *(const uint4*)(vr + s4*8);
        st8(&BKV[tid*36 + s4*8], u);
      } }
    __syncthreads();
    s16x8 ap[4];
    #pragma unroll
    for (int ms = 0; ms < 4; ++ms)
      ap[ms] = ldfrag(&P[(ms*16 + (l & 15))*276 + kt*32 + h*8]);
    #pragma unroll
    for (int ns = 0; ns < 4; ++ns) {
      s16x8 bf = ldfrag(&BKV[(nbase + ns*16 + (l & 15))*36 + h*8]);
      #pragma unroll
      for (int ms = 0; ms < 4; ++ms)
        accO[ms][ns] = __builtin_amdgcn_mfma_f32_16x16x32_bf16(ap[ms], bf, accO[ms][ns], 0,0,0);
    }
  }

  // wide AO store via P reuse
  __syncthreads();
  #pragma unroll
  for (int ms=0;ms<4;ms++)
    #pragma unroll
    for (int j=0;j<4;j++) {
      float rv = rinv[ms][j];
      int q = ms*16 + 4*h + j;
      #pragma unroll
      for (int ns=0;ns<4;ns++)
        P[q*276 + nbase + ns*16 + (l & 15)] = f2bf(accO[ms][ns][j] * rv);
    }
  __syncthreads();
  ushort* aob = AO + (size_t)w*65536;
  #pragma unroll
  for (int it = 0; it < 8; ++it) {
    int task = tid + 256*it;
    int r = task >> 5, seg = task & 31;
    const ushort* sp = &P[r*276 + seg*8];
    uint4 v;
    ((ull*)&v)[0] = *(const ull*)sp;
    ((ull*)&v)[1] = *(const ull*)(sp + 4);
    *(uint4*)(aob + (size_t)(q0 + r)*256 + seg*8) = v;
  }
}

// ---------------- output projection + residual ----------------
__global__ __launch_bounds__(512, 2) void k_oproj(const float* __restrict__ x,
    const ushort* __restrict__ AO, const ushort* __restrict__ woE,
    const float* __restrict__ biasAll, float* __restrict__ y) {
  int g = blockIdx.x;
  int w = (g & 7)*128 + (g >> 3);
  int b = w >> 8, wy = (w >> 4) & 15, wx = w & 15;
  int tid = threadIdx.x, l = tid & 63, wid = tid >> 6, h = l >> 4;
  __shared__ __align__(16) ushort alds[256*36];
  __shared__ __align__(16) ushort wlds[256*36];
  const ushort* abase = AO + (size_t)w*65536;

  f32x4 acc[8][4];
  #pragma unroll
  for (int a=0;a<8;a++)
    #pragma unroll
    for (int n=0;n<4;n++) acc[a][n] = (f32x4){0.f,0.f,0.f,0.f};
  int mbase = (wid >> 2)*128, nbase = (wid & 3)*64;

  for (int ck = 0; ck < 8; ++ck) {
    int cb = ck*32;
    __syncthreads();
    { int row = tid >> 1, sg = (tid & 1)*2;
      #pragma unroll
      for (int q2 = 0; q2 < 2; ++q2) {
        int seg = sg + q2;
        uint4 u  = *(const uint4*)(woE + (size_t)row*256 + cb + seg*8);
        st8(&wlds[row*36 + seg*8], u);
        uint4 u2 = *(const uint4*)(abase + (size_t)row*256 + cb + seg*8);
        st8(&alds[row*36 + seg*8], u2);
      } }
    __syncthreads();
    s16x8 bf[4];
    #pragma unroll
    for (int ns = 0; ns < 4; ++ns)
      bf[ns] = ldfrag(&alds[(nbase + ns*16 + (l & 15))*36 + h*8]);
    #pragma unroll
    for (int ms = 0; ms < 8; ++ms) {
      s16x8 af = ldfrag(&wlds[(mbase + ms*16 + (l & 15))*36 + h*8]);
      #pragma unroll
      for (int ns = 0; ns < 4; ++ns)
        acc[ms][ns] = __builtin_amdgcn_mfma_f32_16x16x32_bf16(af, bf[ns], acc[ms][ns], 0,0,0);
    }
  }
  const float* bs = biasAll + 3072;
  const float* xbase = x + (size_t)b*IMG_ + wy*16*256 + wx*16;
  float* ybase = y + (size_t)b*IMG_ + wy*16*256 + wx*16;
  #pragma unroll
  for (int ms = 0; ms < 8; ++ms) {
    f32x4 b4 = *(const f32x4*)&bs[mbase + ms*16 + 4*h];
    #pragma unroll
    for (int j = 0; j < 4; ++j) {
      int o = mbase + ms*16 + 4*h + j;
      #pragma unroll
      for (int ns = 0; ns < 4; ++ns) {
        int t = nbase + ns*16 + (l & 15);
        size_t off = (size_t)o*HW_ + (t >> 4)*256 + (t & 15);
        ybase[off] = xbase[off] + acc[ms][ns][j] + b4[j];
      }
    }
  }
}

extern "C" void kernel_launch(void* const* d_in, const int* in_sizes, int n_in,
                              void* d_out, int out_size, void* d_ws, size_t ws_size,
                              hipStream_t stream) {
  const float* x     = (const float*)d_in[0];
  const float* gamma = (const float*)d_in[1];
  const float* beta  = (const float*)d_in[2];
  const float* wq = (const float*)d_in[3];
  const float* bq = (const float*)d_in[4];
  const float* wk = (const float*)d_in[5];
  const float* bk = (const float*)d_in[6];
  const float* wv = (const float*)d_in[7];
  const float* bv = (const float*)d_in[8];
  const float* wo = (const float*)d_in[9];
  const float* bo = (const float*)d_in[10];
  float* y = (float*)d_out;
  char* ws = (char*)d_ws;

  float2* part   = (float2*)ws;                        // 8 KB
  float*  biasAll= (float*)(ws + 8192);                // 13.3 KB
  ushort* wAll   = (ushort*)(ws + 32768);              // 1.5 MB
  ushort* woE    = (ushort*)(ws + 32768 + 1572864);    // 128 KB
  ushort* Qt     = (ushort*)(ws + 2097152);            // 134 MB (also AO)
  ushort* Kt = (ushort*)d_out;
  ushort* V  = (ushort*)d_out + (size_t)67108864;

  k_stats1<<<1024, 256, 0, stream>>>(x, part);
  k_fold<<<13, 256, 0, stream>>>(wq,bq,wk,bk,wv,bv,wo,bo,gamma,beta,part,wAll,woE,biasAll);
  k_qkv<<<6144, 256, 0, stream>>>(x, wAll, biasAll, Qt, Kt, V);
  k_attn<<<4096, 256, 0, stream>>>(Qt, Kt, V, Qt /*AO alias: disjoint rows*/);
  k_oproj<<<1024, 512, 0, stream>>>(x, Qt /*AO*/, woE, biasAll, y);
}